// Round 3
// baseline (548.827 us; speedup 1.0000x reference)
//
#include <hip/hip_runtime.h>
#include <stdint.h>

#define M_DIM 8192
#define K_DIM 4096
#define N_DIM 12288

typedef int v4i __attribute__((ext_vector_type(4)));
typedef int v16i __attribute__((ext_vector_type(16)));

#define GLDS16(g, l)                                                         \
  __builtin_amdgcn_global_load_lds(                                          \
      (const __attribute__((address_space(1))) void*)(g),                    \
      (__attribute__((address_space(3))) void*)(l), 16, 0, 0)

#define BARRIER() asm volatile("s_barrier" ::: "memory")
#define VMCNT4() asm volatile("s_waitcnt vmcnt(4)" ::: "memory")
#define VMCNT0() asm volatile("s_waitcnt vmcnt(0)" ::: "memory")

// ---------------------------------------------------------------------------
// Fused prep: blocks [0, M) quantize x rows; blocks [M, M+12288) pack weights.
// Both memory-bound; one launch lets them share the chip and kills the tail.
// ---------------------------------------------------------------------------
__global__ __launch_bounds__(256) void prep(const float* __restrict__ x,
                                            int8_t* __restrict__ xq,
                                            float* __restrict__ xs,
                                            const int* __restrict__ w32,
                                            int8_t* __restrict__ w8) {
  const int t = threadIdx.x;
  if ((int)blockIdx.x < M_DIM) {
    // ---- per-token dynamic int8 quantization ----
    const int row = blockIdx.x;
    const float* xr = x + (size_t)row * K_DIM;

    float4 v[4];
    float amax = 0.f;
#pragma unroll
    for (int i = 0; i < 4; ++i) {
      v[i] = reinterpret_cast<const float4*>(xr)[t * 4 + i];
      amax = fmaxf(amax, fmaxf(fmaxf(fabsf(v[i].x), fabsf(v[i].y)),
                               fmaxf(fabsf(v[i].z), fabsf(v[i].w))));
    }
#pragma unroll
    for (int off = 32; off > 0; off >>= 1)
      amax = fmaxf(amax, __shfl_xor(amax, off));

    __shared__ float smax[4];
    if ((t & 63) == 0) smax[t >> 6] = amax;
    __syncthreads();
    amax = fmaxf(fmaxf(smax[0], smax[1]), fmaxf(smax[2], smax[3]));

    const float scale = fmaxf(amax, 1e-8f) / 127.f;

    union {
      int8_t b[16];
      v4i v;
    } p;
    const float* pv = reinterpret_cast<const float*>(v);
#pragma unroll
    for (int i = 0; i < 16; ++i) {
      float r = rintf(pv[i] / scale);  // round-half-to-even == jnp.round
      r = fminf(127.f, fmaxf(-127.f, r));
      p.b[i] = (int8_t)(int)r;
    }
    reinterpret_cast<v4i*>(xq + (size_t)row * K_DIM)[t] = p.v;
    if (t == 0) xs[row] = scale;
  } else {
    // ---- pack int32-carried weights into int8 ----
    const size_t i = (((size_t)blockIdx.x - M_DIM) * 256 + t) * 16;
    const int4* src = reinterpret_cast<const int4*>(w32 + i);
    union {
      int8_t b[16];
      v4i v;
    } p;
#pragma unroll
    for (int c = 0; c < 4; ++c) {
      int4 q = src[c];
      p.b[c * 4 + 0] = (int8_t)q.x;
      p.b[c * 4 + 1] = (int8_t)q.y;
      p.b[c * 4 + 2] = (int8_t)q.z;
      p.b[c * 4 + 3] = (int8_t)q.w;
    }
    *reinterpret_cast<v4i*>(w8 + i) = p.v;
  }
}

// ---------------------------------------------------------------------------
// int8 GEMM, 256x256 tile, BK=128 bytes, 8 waves (2Mx4N), 8-phase schedule
// with counted vmcnt (T3+T4), LDS XOR swizzle (T2), setprio (T5), XCD block
// swizzle (T1). mfma_i32_32x32x32_i8 (4404 TOPS pipe vs 3944 for 16x16x64).
// LDS byte image identical to round-2; only the fragment read pattern and
// MFMA shape changed.
// ---------------------------------------------------------------------------
#define BM 256
#define BN 256
#define BKB 128                 // K bytes per tile
#define NTILES (K_DIM / BKB)    // 32

__global__ __launch_bounds__(512, 2) void gemm_i8(
    const int8_t* __restrict__ xq, const float* __restrict__ xs,
    const int8_t* __restrict__ w8, const float* __restrict__ wsc,
    const float* __restrict__ bias, float* __restrict__ out) {
  // LDS map: As[c] at c*32768 (256 rows x 128B), Bs[c] at 65536 + c*32768.
  __shared__ __align__(16) int8_t lds[131072];
  const v4i* Lv = (const v4i*)lds;

  const int t = threadIdx.x;
  const int lane = t & 63;
  const int w = t >> 6;      // wave 0..7
  const int wr = w >> 2;     // 0..1 -> 128-row block
  const int wc = w & 3;      // 0..3 -> 64-col block
  const int l31 = lane & 31;
  const int hi = lane >> 5;  // k-chunk half for 32x32 fragments
  const int l7 = lane & 7;

  const int NT_N = N_DIM / BN;            // 48
  const int nwg = (M_DIM / BM) * NT_N;    // 1536, %8==0 -> simple XCD swizzle
  int bid = (int)blockIdx.x;
  bid = (bid & 7) * (nwg >> 3) + (bid >> 3);
  const int rowBase = (bid / NT_N) * BM;
  const int colBase = (bid % NT_N) * BN;

  // staging (unchanged): thread t -> row t>>3, lds 16B-slot t&7; inverse
  // swizzle on the GLOBAL source so lds(R,S) holds global chunk S^(R&7).
  const int srow = t >> 3;
  const int gslot = (t & 7) ^ (srow & 7);
  const int8_t* gA = xq + (size_t)(rowBase + srow) * K_DIM + gslot * 16;
  const int8_t* gB = w8 + (size_t)(colBase + srow) * K_DIM + gslot * 16;
  int8_t* ldsw = lds + w * 1024;  // wave-uniform dest base (HW adds lane*16)

#define STAGE_A(c, r0, k0) \
  GLDS16(gA + (size_t)(r0) * K_DIM + (k0), ldsw + (c) * 32768 + (r0) * 128)
#define STAGE_B(c, r0, k0) \
  GLDS16(gB + (size_t)(r0) * K_DIM + (k0), ldsw + 65536 + (c) * 32768 + (r0) * 128)

  // 32x32 fragment read: desired 16B chunk j*2+hi (j = 32-wide k-slice 0..3),
  // swizzled slot = chunk ^ (row&7); row&7 == lane&7 (frag bases are mult-32).
  const int sl0 = (0 + hi) ^ l7;
  const int sl1 = (2 + hi) ^ l7;
  const int sl2 = (4 + hi) ^ l7;
  const int sl3 = (6 + hi) ^ l7;
  const int rAb = wr * 128 + l31;  // + mh*64 + mi*32
  const int rBb = wc * 64 + l31;   // + ni*32

#define LA(c, mh, mi, sl) \
  Lv[((c) << 11) + ((rAb + (mh) * 64 + (mi) * 32) << 3) + (sl)]
#define LB(c, ni, sl) \
  Lv[4096 + ((c) << 11) + ((rBb + (ni) * 32) << 3) + (sl)]

  v16i acc[4][2];
#pragma unroll
  for (int i = 0; i < 4; ++i)
#pragma unroll
    for (int j = 0; j < 2; ++j)
#pragma unroll
      for (int r = 0; r < 16; ++r) acc[i][j][r] = 0;

  // prologue: tile0 (8 stages, buf0) + tile1 A (4 stages, buf1)
  STAGE_A(0, 0, 0); STAGE_A(0, 64, 0); STAGE_A(0, 128, 0); STAGE_A(0, 192, 0);
  STAGE_B(0, 0, 0); STAGE_B(0, 64, 0); STAGE_B(0, 128, 0); STAGE_B(0, 192, 0);
  STAGE_A(1, 0, BKB); STAGE_A(1, 64, BKB); STAGE_A(1, 128, BKB); STAGE_A(1, 192, BKB);
  VMCNT4();   // tile0 fully landed (4 newest = tile1 A)
  BARRIER();

  v4i af[2][2], bf[2][2];

  // one phase: ds-load subtile, issue stage, barrier, 8x MFMA 32x32x32, barrier
#define PHASE(c, MH, KS2, LOADB, ...)                                          \
  {                                                                            \
    af[0][0] = LA(c, MH, 0, (KS2) ? sl2 : sl0);                                \
    af[0][1] = LA(c, MH, 0, (KS2) ? sl3 : sl1);                                \
    af[1][0] = LA(c, MH, 1, (KS2) ? sl2 : sl0);                                \
    af[1][1] = LA(c, MH, 1, (KS2) ? sl3 : sl1);                                \
    if (LOADB) {                                                               \
      bf[0][0] = LB(c, 0, (KS2) ? sl2 : sl0);                                  \
      bf[0][1] = LB(c, 0, (KS2) ? sl3 : sl1);                                  \
      bf[1][0] = LB(c, 1, (KS2) ? sl2 : sl0);                                  \
      bf[1][1] = LB(c, 1, (KS2) ? sl3 : sl1);                                  \
    }                                                                          \
    __VA_ARGS__                                                                \
    BARRIER();                                                                 \
    __builtin_amdgcn_s_setprio(1);                                             \
    _Pragma("unroll") for (int kk = 0; kk < 2; ++kk)                           \
        _Pragma("unroll") for (int ni = 0; ni < 2; ++ni)                       \
            _Pragma("unroll") for (int mi = 0; mi < 2; ++mi)                   \
                acc[(MH) * 2 + mi][ni] =                                       \
                    __builtin_amdgcn_mfma_i32_32x32x32_i8(                     \
                        af[mi][kk], bf[ni][kk], acc[(MH) * 2 + mi][ni], 0, 0,  \
                        0);                                                    \
    __builtin_amdgcn_s_setprio(0);                                             \
    BARRIER();                                                                 \
  }

  for (int tt = 0; tt < NTILES - 2; ++tt) {
    const int c = tt & 1;
    const int k1 = (tt + 1) * BKB;
    const int k2 = (tt + 2) * BKB;
    PHASE(c, 0, 0, 1, STAGE_B(c ^ 1, 0, k1); STAGE_B(c ^ 1, 64, k1);)
    PHASE(c, 1, 0, 0, STAGE_B(c ^ 1, 128, k1); STAGE_B(c ^ 1, 192, k1);)
    PHASE(c, 0, 1, 1, )
    PHASE(c, 1, 1, 0, )
    // boundary: buf c just freed -> stage tile tt+2's A there, counted wait
    STAGE_A(c, 0, k2); STAGE_A(c, 64, k2); STAGE_A(c, 128, k2); STAGE_A(c, 192, k2);
    VMCNT4();  // all of tile tt+1 landed; only tt+2's 4 A-stages in flight
    BARRIER();
  }
  {  // tt = NTILES-2 (c=0): stage last tile's B, then full drain
    const int k1 = (NTILES - 1) * BKB;
    PHASE(0, 0, 0, 1, STAGE_B(1, 0, k1); STAGE_B(1, 64, k1);)
    PHASE(0, 1, 0, 0, STAGE_B(1, 128, k1); STAGE_B(1, 192, k1);)
    PHASE(0, 0, 1, 1, )
    PHASE(0, 1, 1, 0, )
    VMCNT0();
    BARRIER();
  }
  {  // tt = NTILES-1 (c=1): compute only
    PHASE(1, 0, 0, 1, )
    PHASE(1, 1, 0, 0, )
    PHASE(1, 0, 1, 1, )
    PHASE(1, 1, 1, 0, )
  }

  // epilogue: 32x32 C/D layout: col = lane&31,
  // row = (reg&3) + 8*(reg>>2) + 4*(lane>>5)
  const int orow0 = rowBase + wr * 128;
  const int ocol0 = colBase + wc * 64;
#pragma unroll
  for (int mi = 0; mi < 4; ++mi) {
    const int rbase = orow0 + mi * 32 + hi * 4;
    float sarr[16];
#pragma unroll
    for (int g = 0; g < 4; ++g)
#pragma unroll
      for (int r = 0; r < 4; ++r) sarr[g * 4 + r] = xs[rbase + g * 8 + r];
#pragma unroll
    for (int ni = 0; ni < 2; ++ni) {
      const int col = ocol0 + ni * 32 + l31;
      const float wf = wsc[col];
      const float bb = bias[col];
#pragma unroll
      for (int g = 0; g < 4; ++g)
#pragma unroll
        for (int r = 0; r < 4; ++r) {
          const int row = rbase + g * 8 + r;
          out[(size_t)row * N_DIM + col] =
              (float)acc[mi][ni][g * 4 + r] * sarr[g * 4 + r] * wf + bb;
        }
    }
  }
}

// ---------------------------------------------------------------------------
extern "C" void kernel_launch(void* const* d_in, const int* in_sizes, int n_in,
                              void* d_out, int out_size, void* d_ws,
                              size_t ws_size, hipStream_t stream) {
  const float* x = (const float*)d_in[0];
  const int* w32 = (const int*)d_in[1];
  const float* wscale = (const float*)d_in[2];
  const float* bias = (const float*)d_in[3];
  float* out = (float*)d_out;

  int8_t* xq = (int8_t*)d_ws;
  float* xs = (float*)((char*)d_ws + (size_t)M_DIM * K_DIM);
  int8_t* w8 = (int8_t*)((char*)d_ws + (size_t)M_DIM * K_DIM + M_DIM * 4);

  const int packBlocks = (N_DIM * K_DIM) / (256 * 16);  // 12288
  prep<<<M_DIM + packBlocks, 256, 0, stream>>>(x, xq, xs, w32, w8);
  gemm_i8<<<(M_DIM / BM) * (N_DIM / BN), 512, 0, stream>>>(xq, xs, w8, wscale,
                                                           bias, out);
}

// Round 4
// 548.499 us; speedup vs baseline: 1.0006x; 1.0006x over previous
//
#include <hip/hip_runtime.h>
#include <stdint.h>

#define M_DIM 8192
#define K_DIM 4096
#define N_DIM 12288

typedef int v4i __attribute__((ext_vector_type(4)));
typedef int v16i __attribute__((ext_vector_type(16)));

#define GLDS16(g, l)                                                         \
  __builtin_amdgcn_global_load_lds(                                          \
      (const __attribute__((address_space(1))) void*)(g),                    \
      (__attribute__((address_space(3))) void*)(l), 16, 0, 0)

#define BARRIER() asm volatile("s_barrier" ::: "memory")
#define VMCNT4() asm volatile("s_waitcnt vmcnt(4)" ::: "memory")
#define VMCNT0() asm volatile("s_waitcnt vmcnt(0)" ::: "memory")

// ---------------------------------------------------------------------------
// Fused prep: blocks [0, M) quantize x rows; blocks [M, M+12288) pack weights.
// ---------------------------------------------------------------------------
__global__ __launch_bounds__(256) void prep(const float* __restrict__ x,
                                            int8_t* __restrict__ xq,
                                            float* __restrict__ xs,
                                            const int* __restrict__ w32,
                                            int8_t* __restrict__ w8) {
  const int t = threadIdx.x;
  if ((int)blockIdx.x < M_DIM) {
    const int row = blockIdx.x;
    const float* xr = x + (size_t)row * K_DIM;

    float4 v[4];
    float amax = 0.f;
#pragma unroll
    for (int i = 0; i < 4; ++i) {
      v[i] = reinterpret_cast<const float4*>(xr)[t * 4 + i];
      amax = fmaxf(amax, fmaxf(fmaxf(fabsf(v[i].x), fabsf(v[i].y)),
                               fmaxf(fabsf(v[i].z), fabsf(v[i].w))));
    }
#pragma unroll
    for (int off = 32; off > 0; off >>= 1)
      amax = fmaxf(amax, __shfl_xor(amax, off));

    __shared__ float smax[4];
    if ((t & 63) == 0) smax[t >> 6] = amax;
    __syncthreads();
    amax = fmaxf(fmaxf(smax[0], smax[1]), fmaxf(smax[2], smax[3]));

    const float scale = fmaxf(amax, 1e-8f) / 127.f;

    union {
      int8_t b[16];
      v4i v;
    } p;
    const float* pv = reinterpret_cast<const float*>(v);
#pragma unroll
    for (int i = 0; i < 16; ++i) {
      float r = rintf(pv[i] / scale);  // round-half-to-even == jnp.round
      r = fminf(127.f, fmaxf(-127.f, r));
      p.b[i] = (int8_t)(int)r;
    }
    reinterpret_cast<v4i*>(xq + (size_t)row * K_DIM)[t] = p.v;
    if (t == 0) xs[row] = scale;
  } else {
    const size_t i = (((size_t)blockIdx.x - M_DIM) * 256 + t) * 16;
    const int4* src = reinterpret_cast<const int4*>(w32 + i);
    union {
      int8_t b[16];
      v4i v;
    } p;
#pragma unroll
    for (int c = 0; c < 4; ++c) {
      int4 q = src[c];
      p.b[c * 4 + 0] = (int8_t)q.x;
      p.b[c * 4 + 1] = (int8_t)q.y;
      p.b[c * 4 + 2] = (int8_t)q.z;
      p.b[c * 4 + 3] = (int8_t)q.w;
    }
    *reinterpret_cast<v4i*>(w8 + i) = p.v;
  }
}

// ---------------------------------------------------------------------------
// int8 GEMM, 256x256 tile, BK=128B, 8 waves (2Mx4N), 8-phase counted-vmcnt
// schedule, mfma_i32_32x32x32_i8.
// Swizzle v2: f(R) = (R&7) ^ (((R>>3)&3)<<1). Round-3's f(R)=R&7 made the
// read slot constant across strided-8 lane groups (slot varied only with
// lane bit 5) -> 4-way bank conflict (3.77e7). f now injects lane bits 3-4:
// contiguous-8 AND strided-8 lane groups each cover all 8 slots.
// lds(R,S) holds global chunk S ^ f(R); staging source pre-applies f.
// ---------------------------------------------------------------------------
#define BM 256
#define BN 256
#define BKB 128                 // K bytes per tile
#define NTILES (K_DIM / BKB)    // 32

__global__ __launch_bounds__(512, 2) void gemm_i8(
    const int8_t* __restrict__ xq, const float* __restrict__ xs,
    const int8_t* __restrict__ w8, const float* __restrict__ wsc,
    const float* __restrict__ bias, float* __restrict__ out) {
  // LDS map: As[c] at c*32768 (256 rows x 128B), Bs[c] at 65536 + c*32768.
  __shared__ __align__(16) int8_t lds[131072];
  const v4i* Lv = (const v4i*)lds;

  const int t = threadIdx.x;
  const int lane = t & 63;
  const int w = t >> 6;      // wave 0..7
  const int wr = w >> 2;     // 0..1 -> 128-row block
  const int wc = w & 3;      // 0..3 -> 64-col block
  const int l31 = lane & 31;
  const int hi = lane >> 5;  // k-chunk half for 32x32 fragments

  const int NT_N = N_DIM / BN;            // 48
  const int nwg = (M_DIM / BM) * NT_N;    // 1536, %8==0 -> simple XCD swizzle
  int bid = (int)blockIdx.x;
  bid = (bid & 7) * (nwg >> 3) + (bid >> 3);
  const int rowBase = (bid / NT_N) * BM;
  const int colBase = (bid % NT_N) * BN;

  // staging: thread t -> row srow = t>>3, lds 16B-slot t&7. Global source
  // pre-applies f so lds(R,S) = global chunk S ^ f(R).
  const int srow = t >> 3;
  const int fstg = (srow & 7) ^ (((srow >> 3) & 3) << 1);
  const int gslot = (t & 7) ^ fstg;
  const int8_t* gA = xq + (size_t)(rowBase + srow) * K_DIM + gslot * 16;
  const int8_t* gB = w8 + (size_t)(colBase + srow) * K_DIM + gslot * 16;
  int8_t* ldsw = lds + w * 1024;  // wave-uniform dest base (HW adds lane*16)

#define STAGE_A(c, r0, k0) \
  GLDS16(gA + (size_t)(r0) * K_DIM + (k0), ldsw + (c) * 32768 + (r0) * 128)
#define STAGE_B(c, r0, k0) \
  GLDS16(gB + (size_t)(r0) * K_DIM + (k0), ldsw + 65536 + (c) * 32768 + (r0) * 128)

  // fragment read: row = base + l31 (bases mult-32 with (base>>3)&3 == 0),
  // desired chunk = 2j + hi -> slot = chunk ^ f(row),
  // f(row) = (lane&7) ^ (((lane>>3)&3)<<1).
  const int frd = (lane & 7) ^ (((lane >> 3) & 3) << 1);
  const int sl0 = (0 + hi) ^ frd;
  const int sl1 = (2 + hi) ^ frd;
  const int sl2 = (4 + hi) ^ frd;
  const int sl3 = (6 + hi) ^ frd;
  const int rAb = wr * 128 + l31;  // + mh*64 + mi*32
  const int rBb = wc * 64 + l31;   // + ni*32

#define LA(c, mh, mi, sl) \
  Lv[((c) << 11) + ((rAb + (mh) * 64 + (mi) * 32) << 3) + (sl)]
#define LB(c, ni, sl) \
  Lv[4096 + ((c) << 11) + ((rBb + (ni) * 32) << 3) + (sl)]

  v16i acc[4][2];
#pragma unroll
  for (int i = 0; i < 4; ++i)
#pragma unroll
    for (int j = 0; j < 2; ++j)
#pragma unroll
      for (int r = 0; r < 16; ++r) acc[i][j][r] = 0;

  // prologue: tile0 (8 stages, buf0) + tile1 A (4 stages, buf1)
  STAGE_A(0, 0, 0); STAGE_A(0, 64, 0); STAGE_A(0, 128, 0); STAGE_A(0, 192, 0);
  STAGE_B(0, 0, 0); STAGE_B(0, 64, 0); STAGE_B(0, 128, 0); STAGE_B(0, 192, 0);
  STAGE_A(1, 0, BKB); STAGE_A(1, 64, BKB); STAGE_A(1, 128, BKB); STAGE_A(1, 192, BKB);
  VMCNT4();   // tile0 fully landed (4 newest = tile1 A)
  BARRIER();

  v4i af[2][2], bf[2][2];

#define PHASE(c, MH, KS2, LOADB, ...)                                          \
  {                                                                            \
    af[0][0] = LA(c, MH, 0, (KS2) ? sl2 : sl0);                                \
    af[0][1] = LA(c, MH, 0, (KS2) ? sl3 : sl1);                                \
    af[1][0] = LA(c, MH, 1, (KS2) ? sl2 : sl0);                                \
    af[1][1] = LA(c, MH, 1, (KS2) ? sl3 : sl1);                                \
    if (LOADB) {                                                               \
      bf[0][0] = LB(c, 0, (KS2) ? sl2 : sl0);                                  \
      bf[0][1] = LB(c, 0, (KS2) ? sl3 : sl1);                                  \
      bf[1][0] = LB(c, 1, (KS2) ? sl2 : sl0);                                  \
      bf[1][1] = LB(c, 1, (KS2) ? sl3 : sl1);                                  \
    }                                                                          \
    __VA_ARGS__                                                                \
    BARRIER();                                                                 \
    __builtin_amdgcn_s_setprio(1);                                             \
    _Pragma("unroll") for (int kk = 0; kk < 2; ++kk)                           \
        _Pragma("unroll") for (int ni = 0; ni < 2; ++ni)                       \
            _Pragma("unroll") for (int mi = 0; mi < 2; ++mi)                   \
                acc[(MH) * 2 + mi][ni] =                                       \
                    __builtin_amdgcn_mfma_i32_32x32x32_i8(                     \
                        af[mi][kk], bf[ni][kk], acc[(MH) * 2 + mi][ni], 0, 0,  \
                        0);                                                    \
    __builtin_amdgcn_s_setprio(0);                                             \
    BARRIER();                                                                 \
  }

  for (int tt = 0; tt < NTILES - 2; ++tt) {
    const int c = tt & 1;
    const int k1 = (tt + 1) * BKB;
    const int k2 = (tt + 2) * BKB;
    PHASE(c, 0, 0, 1, STAGE_B(c ^ 1, 0, k1); STAGE_B(c ^ 1, 64, k1);)
    PHASE(c, 1, 0, 0, STAGE_B(c ^ 1, 128, k1); STAGE_B(c ^ 1, 192, k1);)
    PHASE(c, 0, 1, 1, )
    PHASE(c, 1, 1, 0, )
    STAGE_A(c, 0, k2); STAGE_A(c, 64, k2); STAGE_A(c, 128, k2); STAGE_A(c, 192, k2);
    VMCNT4();  // all of tile tt+1 landed; only tt+2's 4 A-stages in flight
    BARRIER();
  }
  {  // tt = NTILES-2 (c=0): stage last tile's B, then full drain
    const int k1 = (NTILES - 1) * BKB;
    PHASE(0, 0, 0, 1, STAGE_B(1, 0, k1); STAGE_B(1, 64, k1);)
    PHASE(0, 1, 0, 0, STAGE_B(1, 128, k1); STAGE_B(1, 192, k1);)
    PHASE(0, 0, 1, 1, )
    PHASE(0, 1, 1, 0, )
    VMCNT0();
    BARRIER();
  }
  {  // tt = NTILES-1 (c=1): compute only
    PHASE(1, 0, 0, 1, )
    PHASE(1, 1, 0, 0, )
    PHASE(1, 0, 1, 1, )
    PHASE(1, 1, 1, 0, )
  }

  // epilogue: 32x32 C/D layout: col = lane&31,
  // row = (reg&3) + 8*(reg>>2) + 4*(lane>>5)
  const int orow0 = rowBase + wr * 128;
  const int ocol0 = colBase + wc * 64;
#pragma unroll
  for (int mi = 0; mi < 4; ++mi) {
    const int rbase = orow0 + mi * 32 + hi * 4;
    float sarr[16];
#pragma unroll
    for (int g = 0; g < 4; ++g)
#pragma unroll
      for (int r = 0; r < 4; ++r) sarr[g * 4 + r] = xs[rbase + g * 8 + r];
#pragma unroll
    for (int ni = 0; ni < 2; ++ni) {
      const int col = ocol0 + ni * 32 + l31;
      const float wf = wsc[col];
      const float bb = bias[col];
#pragma unroll
      for (int g = 0; g < 4; ++g)
#pragma unroll
        for (int r = 0; r < 4; ++r) {
          const int row = rbase + g * 8 + r;
          out[(size_t)row * N_DIM + col] =
              (float)acc[mi][ni][g * 4 + r] * sarr[g * 4 + r] * wf + bb;
        }
    }
  }
}

// ---------------------------------------------------------------------------
extern "C" void kernel_launch(void* const* d_in, const int* in_sizes, int n_in,
                              void* d_out, int out_size, void* d_ws,
                              size_t ws_size, hipStream_t stream) {
  const float* x = (const float*)d_in[0];
  const int* w32 = (const int*)d_in[1];
  const float* wscale = (const float*)d_in[2];
  const float* bias = (const float*)d_in[3];
  float* out = (float*)d_out;

  int8_t* xq = (int8_t*)d_ws;
  float* xs = (float*)((char*)d_ws + (size_t)M_DIM * K_DIM);
  int8_t* w8 = (int8_t*)((char*)d_ws + (size_t)M_DIM * K_DIM + M_DIM * 4);

  const int packBlocks = (N_DIM * K_DIM) / (256 * 16);  // 12288
  prep<<<M_DIM + packBlocks, 256, 0, stream>>>(x, xq, xs, w32, w8);
  gemm_i8<<<(M_DIM / BM) * (N_DIM / BN), 512, 0, stream>>>(xq, xs, w8, wscale,
                                                           bias, out);
}

// Round 5
// 503.512 us; speedup vs baseline: 1.0900x; 1.0893x over previous
//
#include <hip/hip_runtime.h>
#include <stdint.h>

#define M_DIM 8192
#define K_DIM 4096
#define N_DIM 12288

typedef int v4i __attribute__((ext_vector_type(4)));

#define GLDS16(g, l)                                                         \
  __builtin_amdgcn_global_load_lds(                                          \
      (const __attribute__((address_space(1))) void*)(g),                    \
      (__attribute__((address_space(3))) void*)(l), 16, 0, 0)

#define BARRIER() asm volatile("s_barrier" ::: "memory")
#define VMCNT2() asm volatile("s_waitcnt vmcnt(2)" ::: "memory")
#define VMCNT0() asm volatile("s_waitcnt vmcnt(0)" ::: "memory")

// ---------------------------------------------------------------------------
// Fused prep: blocks [0, M) quantize x rows; blocks [M, M+12288) pack weights.
// ---------------------------------------------------------------------------
__global__ __launch_bounds__(256) void prep(const float* __restrict__ x,
                                            int8_t* __restrict__ xq,
                                            float* __restrict__ xs,
                                            const int* __restrict__ w32,
                                            int8_t* __restrict__ w8) {
  const int t = threadIdx.x;
  if ((int)blockIdx.x < M_DIM) {
    const int row = blockIdx.x;
    const float* xr = x + (size_t)row * K_DIM;

    float4 v[4];
    float amax = 0.f;
#pragma unroll
    for (int i = 0; i < 4; ++i) {
      v[i] = reinterpret_cast<const float4*>(xr)[t * 4 + i];
      amax = fmaxf(amax, fmaxf(fmaxf(fabsf(v[i].x), fabsf(v[i].y)),
                               fmaxf(fabsf(v[i].z), fabsf(v[i].w))));
    }
#pragma unroll
    for (int off = 32; off > 0; off >>= 1)
      amax = fmaxf(amax, __shfl_xor(amax, off));

    __shared__ float smax[4];
    if ((t & 63) == 0) smax[t >> 6] = amax;
    __syncthreads();
    amax = fmaxf(fmaxf(smax[0], smax[1]), fmaxf(smax[2], smax[3]));

    const float scale = fmaxf(amax, 1e-8f) / 127.f;

    union {
      int8_t b[16];
      v4i v;
    } p;
    const float* pv = reinterpret_cast<const float*>(v);
#pragma unroll
    for (int i = 0; i < 16; ++i) {
      float r = rintf(pv[i] / scale);  // round-half-to-even == jnp.round
      r = fminf(127.f, fmaxf(-127.f, r));
      p.b[i] = (int8_t)(int)r;
    }
    reinterpret_cast<v4i*>(xq + (size_t)row * K_DIM)[t] = p.v;
    if (t == 0) xs[row] = scale;
  } else {
    const size_t i = (((size_t)blockIdx.x - M_DIM) * 256 + t) * 16;
    const int4* src = reinterpret_cast<const int4*>(w32 + i);
    union {
      int8_t b[16];
      v4i v;
    } p;
#pragma unroll
    for (int c = 0; c < 4; ++c) {
      int4 q = src[c];
      p.b[c * 4 + 0] = (int8_t)q.x;
      p.b[c * 4 + 1] = (int8_t)q.y;
      p.b[c * 4 + 2] = (int8_t)q.z;
      p.b[c * 4 + 3] = (int8_t)q.w;
    }
    *reinterpret_cast<v4i*>(w8 + i) = p.v;
  }
}

// ---------------------------------------------------------------------------
// int8 GEMM: r2's proven 16x16x64 base (0 bank conflicts) + spread-stage
// schedule. 256x256 tile, BK=128B, 8 waves (2Mx4N).
// Stage units per tile: A0..A3 / B0..B3 = 64-row slabs (one GLDS per wave).
// Issue order during tile t (into freed buffer c^1), 2 per phase:
//   P1: B0,B1   P2: B2,B3   P3: A0,A2   P4: A1,A3
// Consumption (collective): P1 needs B0-B3,A0,A2; P2 adds A1,A3.
// Waits: vmcnt(2) post-MFMA at P1 (drains prev A1,A3) and at P4 (drains all
// next tile's P1 needs, keeps its newest A1,A3). 8 barriers/tile, no clump.
// ---------------------------------------------------------------------------
#define BM 256
#define BN 256
#define BKB 128                 // K bytes per tile
#define NTILES (K_DIM / BKB)    // 32

__global__ __launch_bounds__(512, 2) void gemm_i8(
    const int8_t* __restrict__ xq, const float* __restrict__ xs,
    const int8_t* __restrict__ w8, const float* __restrict__ wsc,
    const float* __restrict__ bias, float* __restrict__ out) {
  // LDS map: As[c] at c*32768 (256 rows x 128B), Bs[c] at 65536 + c*32768.
  __shared__ __align__(16) int8_t lds[131072];
  const v4i* Lv = (const v4i*)lds;

  const int t = threadIdx.x;
  const int lane = t & 63;
  const int w = t >> 6;      // wave 0..7
  const int wr = w >> 2;     // 0..1 -> 128-row block
  const int wc = w & 3;      // 0..3 -> 64-col block
  const int fr = lane & 15;
  const int kq = lane >> 4;  // 0..3
  const int l7 = lane & 7;

  const int NT_N = N_DIM / BN;            // 48
  const int nwg = (M_DIM / BM) * NT_N;    // 1536, %8==0 -> simple XCD swizzle
  int bid = (int)blockIdx.x;
  bid = (bid & 7) * (nwg >> 3) + (bid >> 3);
  const int rowBase = (bid / NT_N) * BM;
  const int colBase = (bid % NT_N) * BN;

  // staging: thread t -> row srow = t>>3, lds 16B-slot t&7; inverse swizzle on
  // the GLOBAL source so lds(R,S) holds global chunk S ^ (R&7).
  const int srow = t >> 3;
  const int gslot = (t & 7) ^ (srow & 7);
  const int8_t* gA = xq + (size_t)(rowBase + srow) * K_DIM + gslot * 16;
  const int8_t* gB = w8 + (size_t)(colBase + srow) * K_DIM + gslot * 16;
  int8_t* ldsw = lds + w * 1024;  // wave-uniform dest base (HW adds lane*16)

#define STAGE_A(c, r0, k0) \
  GLDS16(gA + (size_t)(r0) * K_DIM + (k0), ldsw + (c) * 32768 + (r0) * 128)
#define STAGE_B(c, r0, k0) \
  GLDS16(gB + (size_t)(r0) * K_DIM + (k0), ldsw + 65536 + (c) * 32768 + (r0) * 128)

  // fragment read slot: (ks*4 + kq) ^ (row&7); row&7 == l7 (bases mult-16).
  const int s0_ = kq ^ l7;        // ks=0
  const int s1_ = s0_ ^ 4;        // ks=1
  const int rA = wr * 128 + fr;   // + mh*64 + mi*16
  const int rB = wc * 64 + fr;    // + ni*16

#define LA(c, mh, mi, ks) \
  Lv[((c) << 11) + ((rA + (mh) * 64 + (mi) * 16) << 3) + ((ks) ? s1_ : s0_)]
#define LB(c, ni, ks) \
  Lv[4096 + ((c) << 11) + ((rB + (ni) * 16) << 3) + ((ks) ? s1_ : s0_)]

  v4i acc[8][4];
#pragma unroll
  for (int i = 0; i < 8; ++i)
#pragma unroll
    for (int j = 0; j < 4; ++j) acc[i][j] = (v4i){0, 0, 0, 0};

  // prologue: tile0 staged in canonical issue order, then keep newest 2
  // (A1,A3) in flight -- P1 doesn't need them, P2's wait covers them.
  STAGE_B(0, 0, 0); STAGE_B(0, 64, 0); STAGE_B(0, 128, 0); STAGE_B(0, 192, 0);
  STAGE_A(0, 0, 0); STAGE_A(0, 128, 0); STAGE_A(0, 64, 0); STAGE_A(0, 192, 0);
  VMCNT2();
  BARRIER();

  v4i af[4], bf[4];

  // phase: ds_read regs, issue 2 stages, barrier, MFMA burst, optional
  // counted wait, barrier.
#define PHASE(c, MH, KS, LOADB, STG, WAIT)                                    \
  {                                                                           \
    _Pragma("unroll") for (int mi = 0; mi < 4; ++mi)                          \
        af[mi] = LA(c, MH, mi, KS);                                           \
    if (LOADB) {                                                              \
      _Pragma("unroll") for (int ni = 0; ni < 4; ++ni)                        \
          bf[ni] = LB(c, ni, KS);                                             \
    }                                                                         \
    STG;                                                                      \
    BARRIER();                                                                \
    __builtin_amdgcn_s_setprio(1);                                            \
    _Pragma("unroll") for (int ni = 0; ni < 4; ++ni)                          \
        _Pragma("unroll") for (int mi = 0; mi < 4; ++mi)                      \
            acc[(MH) * 4 + mi][ni] = __builtin_amdgcn_mfma_i32_16x16x64_i8(   \
                af[mi], bf[ni], acc[(MH) * 4 + mi][ni], 0, 0, 0);             \
    __builtin_amdgcn_s_setprio(0);                                            \
    WAIT;                                                                     \
    BARRIER();                                                                \
  }

  for (int tt = 0; tt < NTILES - 1; ++tt) {
    const int c = tt & 1;
    const int d = c ^ 1;
    const int k1 = (tt + 1) * BKB;
    PHASE(c, 0, 0, 1, { STAGE_B(d, 0, k1); STAGE_B(d, 64, k1); }, VMCNT2());
    PHASE(c, 1, 0, 0, { STAGE_B(d, 128, k1); STAGE_B(d, 192, k1); }, );
    PHASE(c, 0, 1, 1, { STAGE_A(d, 0, k1); STAGE_A(d, 128, k1); }, );
    PHASE(c, 1, 1, 0, { STAGE_A(d, 64, k1); STAGE_A(d, 192, k1); }, VMCNT2());
  }
  {  // last tile (c = 1): no staging; drain the 2 remaining (A1,A3) at P1
    PHASE(1, 0, 0, 1, , VMCNT0());
    PHASE(1, 1, 0, 0, , );
    PHASE(1, 0, 1, 1, , );
    PHASE(1, 1, 1, 0, , );
  }

  // epilogue: C/D layout col = lane&15, row = (lane>>4)*4 + reg
  const int orow0 = rowBase + wr * 128;
  const int ocol0 = colBase + wc * 64;
  const int rsub = kq * 4;
#pragma unroll
  for (int mi8 = 0; mi8 < 8; ++mi8) {
    const int r0 = orow0 + mi8 * 16 + rsub;
    float s4[4];
#pragma unroll
    for (int r = 0; r < 4; ++r) s4[r] = xs[r0 + r];
#pragma unroll
    for (int ni = 0; ni < 4; ++ni) {
      const int col = ocol0 + ni * 16 + fr;
      const float wf = wsc[col];
      const float bb = bias[col];
#pragma unroll
      for (int r = 0; r < 4; ++r)
        out[(size_t)(r0 + r) * N_DIM + col] =
            (float)acc[mi8][ni][r] * s4[r] * wf + bb;
    }
  }
}

// ---------------------------------------------------------------------------
extern "C" void kernel_launch(void* const* d_in, const int* in_sizes, int n_in,
                              void* d_out, int out_size, void* d_ws,
                              size_t ws_size, hipStream_t stream) {
  const float* x = (const float*)d_in[0];
  const int* w32 = (const int*)d_in[1];
  const float* wscale = (const float*)d_in[2];
  const float* bias = (const float*)d_in[3];
  float* out = (float*)d_out;

  int8_t* xq = (int8_t*)d_ws;
  float* xs = (float*)((char*)d_ws + (size_t)M_DIM * K_DIM);
  int8_t* w8 = (int8_t*)((char*)d_ws + (size_t)M_DIM * K_DIM + M_DIM * 4);

  const int packBlocks = (N_DIM * K_DIM) / (256 * 16);  // 12288
  prep<<<M_DIM + packBlocks, 256, 0, stream>>>(x, xq, xs, w32, w8);
  gemm_i8<<<(M_DIM / BM) * (N_DIM / BN), 512, 0, stream>>>(xq, xs, w8, wscale,
                                                           bias, out);
}

// Round 6
// 461.183 us; speedup vs baseline: 1.1900x; 1.0918x over previous
//
#include <hip/hip_runtime.h>
#include <stdint.h>

#define M_DIM 8192
#define K_DIM 4096
#define N_DIM 12288

typedef int v4i __attribute__((ext_vector_type(4)));

#define GLDS16(g, l)                                                         \
  __builtin_amdgcn_global_load_lds(                                          \
      (const __attribute__((address_space(1))) void*)(g),                    \
      (__attribute__((address_space(3))) void*)(l), 16, 0, 0)

#define BARRIER() asm volatile("s_barrier" ::: "memory")
#define VMCNT2() asm volatile("s_waitcnt vmcnt(2)" ::: "memory")
#define VMCNT0() asm volatile("s_waitcnt vmcnt(0)" ::: "memory")

// ---------------------------------------------------------------------------
// Fused prep: blocks [0, M) quantize x rows; blocks [M, M+12288) pack weights.
// ---------------------------------------------------------------------------
__global__ __launch_bounds__(256) void prep(const float* __restrict__ x,
                                            int8_t* __restrict__ xq,
                                            float* __restrict__ xs,
                                            const int* __restrict__ w32,
                                            int8_t* __restrict__ w8) {
  const int t = threadIdx.x;
  if ((int)blockIdx.x < M_DIM) {
    const int row = blockIdx.x;
    const float* xr = x + (size_t)row * K_DIM;

    float4 v[4];
    float amax = 0.f;
#pragma unroll
    for (int i = 0; i < 4; ++i) {
      v[i] = reinterpret_cast<const float4*>(xr)[t * 4 + i];
      amax = fmaxf(amax, fmaxf(fmaxf(fabsf(v[i].x), fabsf(v[i].y)),
                               fmaxf(fabsf(v[i].z), fabsf(v[i].w))));
    }
#pragma unroll
    for (int off = 32; off > 0; off >>= 1)
      amax = fmaxf(amax, __shfl_xor(amax, off));

    __shared__ float smax[4];
    if ((t & 63) == 0) smax[t >> 6] = amax;
    __syncthreads();
    amax = fmaxf(fmaxf(smax[0], smax[1]), fmaxf(smax[2], smax[3]));

    const float scale = fmaxf(amax, 1e-8f) / 127.f;

    union {
      int8_t b[16];
      v4i v;
    } p;
    const float* pv = reinterpret_cast<const float*>(v);
#pragma unroll
    for (int i = 0; i < 16; ++i) {
      float r = rintf(pv[i] / scale);  // round-half-to-even == jnp.round
      r = fminf(127.f, fmaxf(-127.f, r));
      p.b[i] = (int8_t)(int)r;
    }
    reinterpret_cast<v4i*>(xq + (size_t)row * K_DIM)[t] = p.v;
    if (t == 0) xs[row] = scale;
  } else {
    const size_t i = (((size_t)blockIdx.x - M_DIM) * 256 + t) * 16;
    const int4* src = reinterpret_cast<const int4*>(w32 + i);
    union {
      int8_t b[16];
      v4i v;
    } p;
#pragma unroll
    for (int c = 0; c < 4; ++c) {
      int4 q = src[c];
      p.b[c * 4 + 0] = (int8_t)q.x;
      p.b[c * 4 + 1] = (int8_t)q.y;
      p.b[c * 4 + 2] = (int8_t)q.z;
      p.b[c * 4 + 3] = (int8_t)q.w;
    }
    *reinterpret_cast<v4i*>(w8 + i) = p.v;
  }
}

// ---------------------------------------------------------------------------
// int8 GEMM: r5 core (16x16x64, 0 conflicts, spread-stage, counted vmcnt)
// + addressing fix: tile loop unrolled x2 (literal buffer index) and 4
//   precomputed LDS base pointers -> every fragment read is one
//   ds_read_b128 base+imm, zero per-phase address VALU.
// + L2 fix: per-XCD concurrent window is a 4Mx8N rectangle (12MB/round
//   vs 33MB for the 1-D chunk).
// ---------------------------------------------------------------------------
#define BM 256
#define BN 256
#define BKB 128                 // K bytes per tile
#define NTILES (K_DIM / BKB)    // 32

__global__ __launch_bounds__(512, 2) void gemm_i8(
    const int8_t* __restrict__ xq, const float* __restrict__ xs,
    const int8_t* __restrict__ w8, const float* __restrict__ wsc,
    const float* __restrict__ bias, float* __restrict__ out) {
  // LDS map: A bufs at c*32768 (256 rows x 128B), B bufs at 65536 + c*32768.
  __shared__ __align__(16) int8_t lds[131072];

  const int t = threadIdx.x;
  const int lane = t & 63;
  const int w = t >> 6;      // wave 0..7
  const int wr = w >> 2;     // 0..1 -> 128-row block
  const int wc = w & 3;      // 0..3 -> 64-col block
  const int fr = lane & 15;
  const int kq = lane >> 4;  // 0..3
  const int l7 = lane & 7;

  // 2D XCD swizzle: XCD x owns M-tiles [4x,4x+4); within, consecutive
  // blocks form 4M x 8N rectangles (bijective: 8 xcd * 6 g * 32 j = 1536).
  {
  }
  const int bid = (int)blockIdx.x;
  const int xcd = bid & 7;
  const int q = bid >> 3;    // [0,192)
  const int g = q >> 5;      // [0,6)  N-group of 8
  const int j = q & 31;      // 4M x 8N window
  const int rowBase = (xcd * 4 + (j >> 3)) * BM;
  const int colBase = (g * 8 + (j & 7)) * BN;

  // staging: thread t -> row srow = t>>3, lds 16B-slot t&7; inverse swizzle on
  // the GLOBAL source so lds(R,S) holds global chunk S ^ (R&7).
  const int srow = t >> 3;
  const int gslot = (t & 7) ^ (srow & 7);
  const int8_t* gA = xq + (size_t)(rowBase + srow) * K_DIM + gslot * 16;
  const int8_t* gB = w8 + (size_t)(colBase + srow) * K_DIM + gslot * 16;
  int8_t* ldsw = lds + w * 1024;  // wave-uniform dest base (HW adds lane*16)

#define STAGE_A(c, r0, k0) \
  GLDS16(gA + (size_t)(r0) * K_DIM + (k0), ldsw + (c) * 32768 + (r0) * 128)
#define STAGE_B(c, r0, k0) \
  GLDS16(gB + (size_t)(r0) * K_DIM + (k0), ldsw + 65536 + (c) * 32768 + (r0) * 128)

  // fragment read slot: (ks*4 + kq) ^ (row&7); row&7 == l7 (bases mult-16).
  const int s0_ = kq ^ l7;        // ks=0
  const int s1_ = s0_ ^ 4;        // ks=1
  const int rA = wr * 128 + fr;   // + mh*64 + mi*16
  const int rB = wc * 64 + fr;    // + ni*16

  // Precomputed per-thread LDS base pointers; every read below is then a
  // single ds_read_b128 with a 16-bit immediate (max imm 47104 < 65536).
  const v4i* pA0 = (const v4i*)lds + ((rA << 3) + s0_);
  const v4i* pA1 = (const v4i*)lds + ((rA << 3) + s1_);
  const v4i* pB0 = (const v4i*)(lds + 65536) + ((rB << 3) + s0_);
  const v4i* pB1 = (const v4i*)(lds + 65536) + ((rB << 3) + s1_);

  v4i acc[8][4];
#pragma unroll
  for (int i = 0; i < 8; ++i)
#pragma unroll
    for (int jj = 0; jj < 4; ++jj) acc[i][jj] = (v4i){0, 0, 0, 0};

  // prologue: tile0 staged in canonical issue order; keep newest 2 in flight.
  STAGE_B(0, 0, 0); STAGE_B(0, 64, 0); STAGE_B(0, 128, 0); STAGE_B(0, 192, 0);
  STAGE_A(0, 0, 0); STAGE_A(0, 128, 0); STAGE_A(0, 64, 0); STAGE_A(0, 192, 0);
  VMCNT2();
  BARRIER();

  v4i af[4], bf[4];

  // phase: ds_read regs (base+imm), issue 2 stages, barrier, MFMA burst,
  // optional counted wait, barrier. c/MH/KS are literals at every expansion.
#define PHASE(c, MH, KS, LOADB, STG, WAIT)                                    \
  {                                                                           \
    const v4i* _pa = (KS) ? pA1 : pA0;                                        \
    af[0] = _pa[((c) << 11) + (((MH)*64 + 0) << 3)];                          \
    af[1] = _pa[((c) << 11) + (((MH)*64 + 16) << 3)];                         \
    af[2] = _pa[((c) << 11) + (((MH)*64 + 32) << 3)];                         \
    af[3] = _pa[((c) << 11) + (((MH)*64 + 48) << 3)];                         \
    if (LOADB) {                                                              \
      const v4i* _pb = (KS) ? pB1 : pB0;                                      \
      bf[0] = _pb[((c) << 11) + (0 << 3)];                                    \
      bf[1] = _pb[((c) << 11) + (16 << 3)];                                   \
      bf[2] = _pb[((c) << 11) + (32 << 3)];                                   \
      bf[3] = _pb[((c) << 11) + (48 << 3)];                                   \
    }                                                                         \
    STG;                                                                      \
    BARRIER();                                                                \
    __builtin_amdgcn_s_setprio(1);                                            \
    _Pragma("unroll") for (int ni = 0; ni < 4; ++ni)                          \
        _Pragma("unroll") for (int mi = 0; mi < 4; ++mi)                      \
            acc[(MH) * 4 + mi][ni] = __builtin_amdgcn_mfma_i32_16x16x64_i8(   \
                af[mi], bf[ni], acc[(MH) * 4 + mi][ni], 0, 0, 0);             \
    __builtin_amdgcn_s_setprio(0);                                            \
    WAIT;                                                                     \
    BARRIER();                                                                \
  }

  // one tile with buffer c (literal), staging next tile into d = c^1 at k1.
#define TILE(c, d, k1)                                                        \
  PHASE(c, 0, 0, 1, { STAGE_B(d, 0, k1); STAGE_B(d, 64, k1); }, VMCNT2());    \
  PHASE(c, 1, 0, 0, { STAGE_B(d, 128, k1); STAGE_B(d, 192, k1); }, );         \
  PHASE(c, 0, 1, 1, { STAGE_A(d, 0, k1); STAGE_A(d, 128, k1); }, );           \
  PHASE(c, 1, 1, 0, { STAGE_A(d, 64, k1); STAGE_A(d, 192, k1); }, VMCNT2());

  for (int tt = 0; tt < NTILES - 2; tt += 2) {  // tiles 0..29, stage 1..30
    const int k1a = (tt + 1) * BKB;
    const int k1b = (tt + 2) * BKB;
    TILE(0, 1, k1a);
    TILE(1, 0, k1b);
  }
  TILE(0, 1, (NTILES - 1) * BKB);  // tile 30, stage tile 31
  {  // tile 31 (c = 1): no staging; drain remaining at P1
    PHASE(1, 0, 0, 1, , VMCNT0());
    PHASE(1, 1, 0, 0, , );
    PHASE(1, 0, 1, 1, , );
    PHASE(1, 1, 1, 0, , );
  }

  // epilogue: C/D layout col = lane&15, row = (lane>>4)*4 + reg
  const int orow0 = rowBase + wr * 128;
  const int ocol0 = colBase + wc * 64;
  const int rsub = kq * 4;
#pragma unroll
  for (int mi8 = 0; mi8 < 8; ++mi8) {
    const int r0 = orow0 + mi8 * 16 + rsub;
    float s4[4];
#pragma unroll
    for (int r = 0; r < 4; ++r) s4[r] = xs[r0 + r];
#pragma unroll
    for (int ni = 0; ni < 4; ++ni) {
      const int col = ocol0 + ni * 16 + fr;
      const float wf = wsc[col];
      const float bb = bias[col];
#pragma unroll
      for (int r = 0; r < 4; ++r)
        out[(size_t)(r0 + r) * N_DIM + col] =
            (float)acc[mi8][ni][r] * s4[r] * wf + bb;
    }
  }
}

// ---------------------------------------------------------------------------
extern "C" void kernel_launch(void* const* d_in, const int* in_sizes, int n_in,
                              void* d_out, int out_size, void* d_ws,
                              size_t ws_size, hipStream_t stream) {
  const float* x = (const float*)d_in[0];
  const int* w32 = (const int*)d_in[1];
  const float* wscale = (const float*)d_in[2];
  const float* bias = (const float*)d_in[3];
  float* out = (float*)d_out;

  int8_t* xq = (int8_t*)d_ws;
  float* xs = (float*)((char*)d_ws + (size_t)M_DIM * K_DIM);
  int8_t* w8 = (int8_t*)((char*)d_ws + (size_t)M_DIM * K_DIM + M_DIM * 4);

  const int packBlocks = (N_DIM * K_DIM) / (256 * 16);  // 12288
  prep<<<M_DIM + packBlocks, 256, 0, stream>>>(x, xq, xs, w32, w8);
  gemm_i8<<<(M_DIM / BM) * (N_DIM / BN), 512, 0, stream>>>(xq, xs, w8, wscale,
                                                           bias, out);
}